// Round 3
// baseline (1468.524 us; speedup 1.0000x reference)
//
#include <hip/hip_runtime.h>

#define BB 8
#define NN 2048
#define KK 16
#define HH 4
#define DPTS 128
#define DM 256
#define HD 64
#define BN (BB*NN)   // 16384

// ---------------- kernel 1: per-point squared norm ----------------
__global__ __launch_bounds__(256) void k_sq(const float* __restrict__ xyz,
                                            float* __restrict__ sq) {
    int i = blockIdx.x * 256 + threadIdx.x;   // 0..BN-1
    float x = xyz[(size_t)i*3+0], y = xyz[(size_t)i*3+1], z = xyz[(size_t)i*3+2];
    sq[i] = x*x + y*y + z*z;
}

// ---------------- kernel 2: KNN (stable-argsort top-16) ----------------
// One wave per query point. 32 candidates per lane held in registers as
// packed u64 keys (order-flipped float bits << 32 | index) so lexicographic
// (dist, idx) min == stable argsort order. 16 rounds of "min key > prev".
__global__ __launch_bounds__(256) void k_knn(const float* __restrict__ xyz,
                                             const float* __restrict__ sq,
                                             int* __restrict__ knn) {
    int wave = threadIdx.x >> 6;
    int lane = threadIdx.x & 63;
    int p = blockIdx.x * 4 + wave;            // 0..BN-1
    int b = p >> 11;
    int n = p & (NN-1);
    const float* xb = xyz + (size_t)b * NN * 3;
    const float* sb = sq + (size_t)b * NN;
    float qx = xb[n*3+0], qy = xb[n*3+1], qz = xb[n*3+2];
    float qs = sb[n];
    unsigned long long pk[32];
#pragma unroll
    for (int j = 0; j < 32; ++j) {
        int m = lane + 64*j;
        float mx = xb[m*3+0], my = xb[m*3+1], mz = xb[m*3+2];
        float dot = qx*mx + qy*my + qz*mz;
        float d = qs + sb[m] - 2.0f*dot;
        unsigned u = __float_as_uint(d);
        u ^= (u & 0x80000000u) ? 0xffffffffu : 0x80000000u;  // monotone key
        pk[j] = ((unsigned long long)u << 32) | (unsigned)m;
    }
    unsigned long long prev = 0;   // all real keys > 0
    int* out = knn + (size_t)p * KK;
    for (int r = 0; r < KK; ++r) {
        unsigned long long best = ~0ull;
#pragma unroll
        for (int j = 0; j < 32; ++j) {
            unsigned long long c = (pk[j] > prev) ? pk[j] : ~0ull;
            best = (c < best) ? c : best;
        }
#pragma unroll
        for (int off = 32; off >= 1; off >>= 1) {
            unsigned long long o = __shfl_xor(best, off, 64);
            best = (o < best) ? o : best;
        }
        if (lane == 0) out[r] = (int)(best & 0xffffffffu);
        prev = best;
    }
}

// ---------------- kernel 3: x = features @ fc1_w + fc1_b ----------------
// 32 rows per WG. Feature tile stored TRANSPOSED in LDS (stride 36) so the
// inner loop is 2 broadcast float4 LDS reads + 1 coalesced weight float4.
__global__ __launch_bounds__(256) void k_fc1(const float* __restrict__ feat,
                                             const float* __restrict__ w,
                                             const float* __restrict__ bias,
                                             float* __restrict__ x) {
    __shared__ float ft[DPTS*36];
    int tid = threadIdx.x;
    size_t row0 = (size_t)blockIdx.x * 32;
#pragma unroll
    for (int j = 0; j < 16; ++j) {
        int i = tid + 256*j;                 // i = r*128 + k
        int r = i >> 7, k = i & 127;
        ft[k*36 + r] = feat[row0*DPTS + i];
    }
    __syncthreads();
    int rg = tid >> 6, cg = tid & 63;
    int r0 = rg*8, c0 = cg*4;
    float4 bv = *(const float4*)(bias + c0);
    float acc[8][4];
#pragma unroll
    for (int i = 0; i < 8; ++i) { acc[i][0]=bv.x; acc[i][1]=bv.y; acc[i][2]=bv.z; acc[i][3]=bv.w; }
#pragma unroll 4
    for (int k = 0; k < DPTS; ++k) {
        float4 a0 = *(const float4*)(ft + k*36 + r0);
        float4 a1 = *(const float4*)(ft + k*36 + r0 + 4);
        float4 wv = *(const float4*)(w + (size_t)k*DM + c0);
        float av[8] = {a0.x,a0.y,a0.z,a0.w,a1.x,a1.y,a1.z,a1.w};
#pragma unroll
        for (int i = 0; i < 8; ++i) {
            acc[i][0] += av[i]*wv.x; acc[i][1] += av[i]*wv.y;
            acc[i][2] += av[i]*wv.z; acc[i][3] += av[i]*wv.w;
        }
    }
#pragma unroll
    for (int i = 0; i < 8; ++i)
        *(float4*)(x + (row0 + r0 + i)*DM + c0) =
            make_float4(acc[i][0],acc[i][1],acc[i][2],acc[i][3]);
}

// ---------------- kernel 4: q/k/v = x @ {wq,wk,wv} ----------------
__global__ __launch_bounds__(256) void k_qkv(const float* __restrict__ x,
                                             const float* __restrict__ wq,
                                             const float* __restrict__ wk,
                                             const float* __restrict__ wv,
                                             float* __restrict__ q,
                                             float* __restrict__ kb,
                                             float* __restrict__ vb) {
    __shared__ float xt[DM*36];
    int tid = threadIdx.x;
    size_t row0 = (size_t)blockIdx.x * 32;
#pragma unroll
    for (int j = 0; j < 32; ++j) {
        int i = tid + 256*j;                 // i = r*256 + k
        int r = i >> 8, k = i & 255;
        xt[k*36 + r] = x[row0*DM + i];
    }
    __syncthreads();
    int rg = tid >> 6, cg = tid & 63;
    int r0 = rg*8, c0 = cg*4;
    for (int m = 0; m < 3; ++m) {
        const float* w = (m==0) ? wq : ((m==1) ? wk : wv);
        float* o = (m==0) ? q : ((m==1) ? kb : vb);
        float acc[8][4];
#pragma unroll
        for (int i = 0; i < 8; ++i) { acc[i][0]=0.f; acc[i][1]=0.f; acc[i][2]=0.f; acc[i][3]=0.f; }
#pragma unroll 4
        for (int k = 0; k < DM; ++k) {
            float4 a0 = *(const float4*)(xt + k*36 + r0);
            float4 a1 = *(const float4*)(xt + k*36 + r0 + 4);
            float4 wv4 = *(const float4*)(w + (size_t)k*DM + c0);
            float av[8] = {a0.x,a0.y,a0.z,a0.w,a1.x,a1.y,a1.z,a1.w};
#pragma unroll
            for (int i = 0; i < 8; ++i) {
                acc[i][0] += av[i]*wv4.x; acc[i][1] += av[i]*wv4.y;
                acc[i][2] += av[i]*wv4.z; acc[i][3] += av[i]*wv4.w;
            }
        }
#pragma unroll
        for (int i = 0; i < 8; ++i)
            *(float4*)(o + (row0 + r0 + i)*DM + c0) =
                make_float4(acc[i][0],acc[i][1],acc[i][2],acc[i][3]);
    }
}

// ---------------- kernel 5: fused pos-MLP + gamma-MLP + softmax + PV ----------------
// One 256-thread WG per point (b,n). LDS ~52 KB -> 3 WGs/CU.
__global__ __launch_bounds__(256) void k_attn(
    const float* __restrict__ xyz, const float* __restrict__ qbuf,
    const float* __restrict__ kbuf, const float* __restrict__ vbuf,
    const int* __restrict__ knn,
    const float* __restrict__ dw1, const float* __restrict__ db1,
    const float* __restrict__ dw2, const float* __restrict__ db2,
    const float* __restrict__ gw1, const float* __restrict__ gb1,
    const float* __restrict__ gw2, const float* __restrict__ gb2,
    float* __restrict__ res, float* __restrict__ attn_out)
{
    __shared__ float qv[DM];
    __shared__ float rel[KK][4];
    __shared__ int   kidx[KK];
    __shared__ float hA[4160];        // union: hT[256][16] (4096) | A/L[64][65] (4160)
    __shared__ float pos[KK*DM];      // [16][256]
    __shared__ float T[64*68];        // [64] rows, stride 68

    int tid = threadIdx.x;
    int p = blockIdx.x;
    int b = p >> 11, n = p & (NN-1);
    size_t pb = (size_t)p;

    qv[tid] = qbuf[pb*DM + tid];
    if (tid < KK) kidx[tid] = knn[pb*KK + tid];
    __syncthreads();
    if (tid < KK*3) {
        int k = tid / 3, ax = tid % 3;
        rel[k][ax] = xyz[((size_t)b*NN + n)*3 + ax]
                   - xyz[((size_t)b*NN + kidx[k])*3 + ax];
    }
    __syncthreads();

    // phase B: hidden = relu(rel @ dw1 + db1), stored transposed hT[c][k]
    {
        int c = tid;
        float w0 = dw1[c], w1 = dw1[DM + c], w2 = dw1[2*DM + c];
        float bb = db1[c];
        float hk[KK];
#pragma unroll
        for (int k = 0; k < KK; ++k) {
            float t = rel[k][0]*w0 + rel[k][1]*w1 + rel[k][2]*w2 + bb;
            hk[k] = fmaxf(t, 0.f);
        }
#pragma unroll
        for (int k4 = 0; k4 < 4; ++k4)
            *(float4*)(hA + c*16 + k4*4) =
                make_float4(hk[k4*4],hk[k4*4+1],hk[k4*4+2],hk[k4*4+3]);
    }
    __syncthreads();

    // phase C: pos = hidden @ dw2 + db2. thread=(kg,cg): 4 k x 4 c outputs.
    {
        int kg = tid >> 6, cg = tid & 63;
        int k0 = kg*4, c0 = cg*4;
        float4 bv = *(const float4*)(db2 + c0);
        float acc[4][4];
#pragma unroll
        for (int i=0;i<4;++i){acc[i][0]=bv.x;acc[i][1]=bv.y;acc[i][2]=bv.z;acc[i][3]=bv.w;}
#pragma unroll 4
        for (int h = 0; h < DM; ++h) {
            float4 hv = *(const float4*)(hA + h*16 + k0);      // wave-uniform broadcast
            float4 wv = *(const float4*)(dw2 + (size_t)h*DM + c0);
            float hvv[4] = {hv.x,hv.y,hv.z,hv.w};
#pragma unroll
            for (int i=0;i<4;++i){
                acc[i][0]+=hvv[i]*wv.x; acc[i][1]+=hvv[i]*wv.y;
                acc[i][2]+=hvv[i]*wv.z; acc[i][3]+=hvv[i]*wv.w;
            }
        }
#pragma unroll
        for (int i=0;i<4;++i)
            *(float4*)(pos + (k0+i)*DM + c0) =
                make_float4(acc[i][0],acc[i][1],acc[i][2],acc[i][3]);
    }
    __syncthreads();

    // phase D: A[row=(4k+hh)][d] = q - k_gather + pos ; v kept in registers
    float vnr[KK];
    {
        int c = tid, hh = c >> 6, d = c & 63;
        float qc = qv[c];
#pragma unroll
        for (int k = 0; k < KK; ++k) {
            size_t g = ((size_t)b*NN + kidx[k])*DM + c;
            float kv = kbuf[g];
            vnr[k] = vbuf[g];
            hA[(4*k+hh)*65 + d] = (qc - kv) + pos[k*DM + c];
        }
    }
    __syncthreads();

    // phase E: T = relu(A @ gw1 + gb1). thread=(rg,cg): 4 rows x 4 cols.
    {
        int rg = tid >> 4, cg = tid & 15;
        int r0 = rg*4, c0 = cg*4;
        float4 bv = *(const float4*)(gb1 + c0);
        float acc[4][4];
#pragma unroll
        for (int i=0;i<4;++i){acc[i][0]=bv.x;acc[i][1]=bv.y;acc[i][2]=bv.z;acc[i][3]=bv.w;}
#pragma unroll 4
        for (int h = 0; h < HD; ++h) {
            float av[4];
#pragma unroll
            for (int i=0;i<4;++i) av[i] = hA[(r0+i)*65 + h];
            float4 wv = *(const float4*)(gw1 + h*HD + c0);
#pragma unroll
            for (int i=0;i<4;++i){
                acc[i][0]+=av[i]*wv.x; acc[i][1]+=av[i]*wv.y;
                acc[i][2]+=av[i]*wv.z; acc[i][3]+=av[i]*wv.w;
            }
        }
#pragma unroll
        for (int i=0;i<4;++i)
            *(float4*)(T + (r0+i)*68 + c0) =
                make_float4(fmaxf(acc[i][0],0.f),fmaxf(acc[i][1],0.f),
                            fmaxf(acc[i][2],0.f),fmaxf(acc[i][3],0.f));
    }
    __syncthreads();

    // phase F: L = T @ gw2 + gb2 -> stored back into hA (stride 65)
    {
        int rg = tid >> 4, cg = tid & 15;
        int r0 = rg*4, c0 = cg*4;
        float4 bv = *(const float4*)(gb2 + c0);
        float acc[4][4];
#pragma unroll
        for (int i=0;i<4;++i){acc[i][0]=bv.x;acc[i][1]=bv.y;acc[i][2]=bv.z;acc[i][3]=bv.w;}
#pragma unroll 4
        for (int h = 0; h < HD; ++h) {
            float av[4];
#pragma unroll
            for (int i=0;i<4;++i) av[i] = T[(r0+i)*68 + h];
            float4 wv = *(const float4*)(gw2 + h*HD + c0);
#pragma unroll
            for (int i=0;i<4;++i){
                acc[i][0]+=av[i]*wv.x; acc[i][1]+=av[i]*wv.y;
                acc[i][2]+=av[i]*wv.z; acc[i][3]+=av[i]*wv.w;
            }
        }
#pragma unroll
        for (int i=0;i<4;++i){
            hA[(r0+i)*65 + c0+0] = acc[i][0];
            hA[(r0+i)*65 + c0+1] = acc[i][1];
            hA[(r0+i)*65 + c0+2] = acc[i][2];
            hA[(r0+i)*65 + c0+3] = acc[i][3];
        }
    }
    __syncthreads();

    // phase G: softmax over k per channel, write attn_out (streaming -> nontemporal)
    float attnv[KK];
    {
        int hh = tid >> 6, d = tid & 63;
        float s[KK];
#pragma unroll
        for (int k=0;k<KK;++k) s[k] = hA[(4*k+hh)*65 + d] * 0.125f;
        float mx = s[0];
#pragma unroll
        for (int k=1;k<KK;++k) mx = fmaxf(mx, s[k]);
        float sum = 0.f;
#pragma unroll
        for (int k=0;k<KK;++k){ s[k] = __expf(s[k]-mx); sum += s[k]; }
        float inv = 1.0f / sum;
        size_t base = (((size_t)(b*HH+hh)*NN + n)*KK)*HD + d;
#pragma unroll
        for (int k=0;k<KK;++k){
            attnv[k] = s[k]*inv;
            // attn_out is write-once streaming output (256 MB): bypass L2 so
            // dw2 / gathered k,v rows stay resident.
            __builtin_nontemporal_store(attnv[k], attn_out + base + (size_t)k*HD);
        }
    }
    // phase H: res = sum_k attn * (v + pos)
    {
        int c = tid;
        float r = 0.f;
#pragma unroll
        for (int k=0;k<KK;++k) r += attnv[k]*(vnr[k] + pos[k*DM + c]);
        res[pb*DM + c] = r;
    }
}

// ---------------- kernel 6: proj -> LN1 -> fc2 -> LN2 -> +features ----------------
__global__ __launch_bounds__(256) void k_final(
    const float* __restrict__ resbuf, const float* __restrict__ feat,
    const float* __restrict__ proj_w,
    const float* __restrict__ fc2_w, const float* __restrict__ fc2_b,
    const float* __restrict__ ln1g, const float* __restrict__ ln1b,
    const float* __restrict__ ln2g, const float* __restrict__ ln2b,
    float* __restrict__ out)
{
    __shared__ float rT[DM*17];        // transposed res tile [h=256][16], stride 17
    __shared__ float y[16*260];        // y1 [16][256] stride 260
    __shared__ float z[16*132];        // y2 [16][128] stride 132
    __shared__ float stats[16][2];
    int tid = threadIdx.x;
    size_t row0 = (size_t)blockIdx.x * 16;

    // stride-17 writes: tid*17 mod 32 spans all banks -> conflict-free
#pragma unroll
    for (int j = 0; j < 16; ++j)
        rT[tid*17 + j] = resbuf[(row0+j)*DM + tid];
    __syncthreads();

    // proj matvec: thread=(rg,cg): 4 rows x 4 cols
    int rg = tid >> 6, cg = tid & 63;
    int r0 = rg*4, c0 = cg*4;
    {
        float acc[4][4];
#pragma unroll
        for (int i=0;i<4;++i){acc[i][0]=0.f;acc[i][1]=0.f;acc[i][2]=0.f;acc[i][3]=0.f;}
#pragma unroll 4
        for (int h = 0; h < DM; ++h) {
            // rg is wave-uniform -> these are LDS broadcasts (no conflict)
            float avv[4];
#pragma unroll
            for (int i=0;i<4;++i) avv[i] = rT[h*17 + r0 + i];
            float4 wv = *(const float4*)(proj_w + (size_t)h*DM + c0);
#pragma unroll
            for (int i=0;i<4;++i){
                acc[i][0]+=avv[i]*wv.x; acc[i][1]+=avv[i]*wv.y;
                acc[i][2]+=avv[i]*wv.z; acc[i][3]+=avv[i]*wv.w;
            }
        }
#pragma unroll
        for (int i=0;i<4;++i)
            *(float4*)(y + (r0+i)*260 + c0) =
                make_float4(acc[i][0],acc[i][1],acc[i][2],acc[i][3]);
    }
    __syncthreads();

    // LN1 stats (two-pass var to match jnp.var)
    {
        int w = tid >> 6, lane = tid & 63;
#pragma unroll
        for (int i = 0; i < 4; ++i) {
            int r = w*4 + i;
            float4 v = *(const float4*)(y + r*260 + lane*4);
            float sm = v.x+v.y+v.z+v.w;
#pragma unroll
            for (int off = 32; off >= 1; off >>= 1) sm += __shfl_xor(sm, off, 64);
            float mean = sm * (1.0f/256.0f);
            float dx = v.x-mean, dy = v.y-mean, dz = v.z-mean, dw = v.w-mean;
            float vs = dx*dx+dy*dy+dz*dz+dw*dw;
#pragma unroll
            for (int off = 32; off >= 1; off >>= 1) vs += __shfl_xor(vs, off, 64);
            float var = vs * (1.0f/256.0f);
            if (lane == 0) { stats[r][0] = mean; stats[r][1] = 1.0f/sqrtf(var + 1e-5f); }
        }
    }
    __syncthreads();
    // apply LN1 in place (thread owns column tid of every row)
    {
        float g = ln1g[tid], bb = ln1b[tid];
#pragma unroll
        for (int j = 0; j < 16; ++j) {
            float m = stats[j][0], rs = stats[j][1];
            y[j*260 + tid] = (y[j*260 + tid] - m)*rs*g + bb;
        }
    }
    __syncthreads();

    // fc2: thread=(rg2 rows x2, cg2 cols x4)
    {
        int rg2 = tid >> 5, cg2 = tid & 31;
        int rr0 = rg2*2, cc0 = cg2*4;
        float4 bv = *(const float4*)(fc2_b + cc0);
        float acc[2][4];
#pragma unroll
        for (int i=0;i<2;++i){acc[i][0]=bv.x;acc[i][1]=bv.y;acc[i][2]=bv.z;acc[i][3]=bv.w;}
#pragma unroll 4
        for (int h = 0; h < DM; ++h) {
            float a0 = y[(rr0+0)*260 + h];
            float a1 = y[(rr0+1)*260 + h];
            float4 wv = *(const float4*)(fc2_w + (size_t)h*DPTS + cc0);
            acc[0][0]+=a0*wv.x; acc[0][1]+=a0*wv.y; acc[0][2]+=a0*wv.z; acc[0][3]+=a0*wv.w;
            acc[1][0]+=a1*wv.x; acc[1][1]+=a1*wv.y; acc[1][2]+=a1*wv.z; acc[1][3]+=a1*wv.w;
        }
#pragma unroll
        for (int i=0;i<2;++i)
            *(float4*)(z + (rr0+i)*132 + cc0) =
                make_float4(acc[i][0],acc[i][1],acc[i][2],acc[i][3]);
    }
    __syncthreads();

    // LN2 stats over 128
    {
        int w = tid >> 6, lane = tid & 63;
#pragma unroll
        for (int i = 0; i < 4; ++i) {
            int r = w*4 + i;
            float2 v = *(const float2*)(z + r*132 + lane*2);
            float sm = v.x + v.y;
#pragma unroll
            for (int off = 32; off >= 1; off >>= 1) sm += __shfl_xor(sm, off, 64);
            float mean = sm * (1.0f/128.0f);
            float dx = v.x-mean, dy = v.y-mean;
            float vs = dx*dx + dy*dy;
#pragma unroll
            for (int off = 32; off >= 1; off >>= 1) vs += __shfl_xor(vs, off, 64);
            float var = vs * (1.0f/128.0f);
            if (lane == 0) { stats[r][0] = mean; stats[r][1] = 1.0f/sqrtf(var + 1e-5f); }
        }
    }
    __syncthreads();
    // LN2 apply + residual + store
    {
        int hh = tid & 127;
        float g = ln2g[hh], bb = ln2b[hh];
#pragma unroll
        for (int j = 0; j < 8; ++j) {
            int r = (tid >> 7) + 2*j;
            float m = stats[r][0], rs = stats[r][1];
            float val = (z[r*132 + hh] - m)*rs*g + bb + feat[(row0+r)*DPTS + hh];
            out[(row0+r)*DPTS + hh] = val;
        }
    }
}

// ---------------- launcher ----------------
extern "C" void kernel_launch(void* const* d_in, const int* in_sizes, int n_in,
                              void* d_out, int out_size, void* d_ws, size_t ws_size,
                              hipStream_t stream)
{
    (void)in_sizes; (void)n_in; (void)out_size; (void)ws_size;
    const float* xyz      = (const float*)d_in[0];
    const float* features = (const float*)d_in[1];
    const float* fc1_w    = (const float*)d_in[2];
    const float* fc1_b    = (const float*)d_in[3];
    const float* fc2_w    = (const float*)d_in[4];
    const float* fc2_b    = (const float*)d_in[5];
    const float* dw1      = (const float*)d_in[6];
    const float* db1      = (const float*)d_in[7];
    const float* dw2      = (const float*)d_in[8];
    const float* db2      = (const float*)d_in[9];
    const float* gw1      = (const float*)d_in[10];
    const float* gb1      = (const float*)d_in[11];
    const float* gw2      = (const float*)d_in[12];
    const float* gb2      = (const float*)d_in[13];
    const float* wq       = (const float*)d_in[14];
    const float* wk       = (const float*)d_in[15];
    const float* wv       = (const float*)d_in[16];
    const float* proj_w   = (const float*)d_in[17];
    const float* ln1g     = (const float*)d_in[18];
    const float* ln1b     = (const float*)d_in[19];
    const float* ln2g     = (const float*)d_in[20];
    const float* ln2b     = (const float*)d_in[21];
    float* out = (float*)d_out;

    char* ws = (char*)d_ws;
    float* sq   = (float*)(ws + 0);          //  64 KB
    int*   knn  = (int*)  (ws + 65536);      //   1 MB
    float* xbuf = (float*)(ws + 1114112);    //  16 MB (aliased as res later)
    float* qb   = (float*)(ws + 17891328);   //  16 MB
    float* kb   = (float*)(ws + 34668544);   //  16 MB
    float* vb   = (float*)(ws + 51445760);   //  16 MB  -> total ~68 MB
    float* resb = xbuf;                      // x dead after k_qkv

    k_sq  <<<BN/256, 256, 0, stream>>>(xyz, sq);
    k_knn <<<BN/4,   256, 0, stream>>>(xyz, sq, knn);
    k_fc1 <<<BN/32,  256, 0, stream>>>(features, fc1_w, fc1_b, xbuf);
    k_qkv <<<BN/32,  256, 0, stream>>>(xbuf, wq, wk, wv, qb, kb, vb);
    k_attn<<<BN,     256, 0, stream>>>(xyz, qb, kb, vb, knn,
                                       dw1, db1, dw2, db2,
                                       gw1, gb1, gw2, gb2,
                                       resb, out + (size_t)BN*DPTS);
    k_final<<<BN/16, 256, 0, stream>>>(resb, features, proj_w, fc2_w, fc2_b,
                                       ln1g, ln1b, ln2g, ln2b, out);
}

// Round 10
// 825.999 us; speedup vs baseline: 1.7779x; 1.7779x over previous
//
#include <hip/hip_runtime.h>

#define BB 8
#define NN 2048
#define KK 16
#define HH 4
#define DPTS 128
#define DM 256
#define HD 64
#define BN (BB*NN)   // 16384

typedef __attribute__((ext_vector_type(8))) short short8_t;   // 8 bf16 (4 VGPRs)
typedef __attribute__((ext_vector_type(4))) float f32x4;

__device__ __forceinline__ unsigned short f2b(float f) {      // fp32 -> bf16 RNE
    unsigned u = __float_as_uint(f);
    return (unsigned short)((u + 0x7fffu + ((u >> 16) & 1u)) >> 16);
}

// ---------------- kernel 0: pre-convert weights to swizzled bf16 fragments ----
// Fragment layout (16x16x32 bf16 MFMA): frag[(ct*NK + kc)*64 + lane] holds 8
// bf16: B[kc*32 + (lane>>4)*8 + j][ct*16 + (lane&15)], j=0..7. Per-lane 16B
// global loads in k_attn are then perfectly coalesced.
__global__ __launch_bounds__(256) void k_prep(const float* __restrict__ dw2,
                                              const float* __restrict__ gw1,
                                              const float* __restrict__ gw2,
                                              short8_t* __restrict__ dw2b,
                                              short8_t* __restrict__ gw1b,
                                              short8_t* __restrict__ gw2b) {
    int t = blockIdx.x * 256 + threadIdx.x;
    if (t < 8192) {                       // dw2: 16 ct x 8 kc x 64 lanes
        int l = t & 63, kc = (t >> 6) & 7, ct = t >> 9;
        int rb = kc*32 + (l >> 4)*8, col = ct*16 + (l & 15);
        short8_t v;
#pragma unroll
        for (int j = 0; j < 8; ++j) v[j] = (short)f2b(dw2[(size_t)(rb + j)*DM + col]);
        dw2b[t] = v;
    } else if (t < 8704) {                // gw1: 4 ct x 2 kc x 64
        int u = t - 8192;
        int l = u & 63, kc = (u >> 6) & 1, ct = u >> 7;
        int rb = kc*32 + (l >> 4)*8, col = ct*16 + (l & 15);
        short8_t v;
#pragma unroll
        for (int j = 0; j < 8; ++j) v[j] = (short)f2b(gw1[(rb + j)*HD + col]);
        gw1b[u] = v;
    } else if (t < 9216) {                // gw2
        int u = t - 8704;
        int l = u & 63, kc = (u >> 6) & 1, ct = u >> 7;
        int rb = kc*32 + (l >> 4)*8, col = ct*16 + (l & 15);
        short8_t v;
#pragma unroll
        for (int j = 0; j < 8; ++j) v[j] = (short)f2b(gw2[(rb + j)*HD + col]);
        gw2b[u] = v;
    }
}

// ---------------- kernel 1: per-point squared norm ----------------
__global__ __launch_bounds__(256) void k_sq(const float* __restrict__ xyz,
                                            float* __restrict__ sq) {
    int i = blockIdx.x * 256 + threadIdx.x;
    float x = xyz[(size_t)i*3+0], y = xyz[(size_t)i*3+1], z = xyz[(size_t)i*3+2];
    sq[i] = x*x + y*y + z*z;
}

// ---------------- kernel 2: KNN (stable-argsort top-16) ----------------
__global__ __launch_bounds__(256) void k_knn(const float* __restrict__ xyz,
                                             const float* __restrict__ sq,
                                             int* __restrict__ knn) {
    int wave = threadIdx.x >> 6;
    int lane = threadIdx.x & 63;
    int p = blockIdx.x * 4 + wave;
    int b = p >> 11;
    int n = p & (NN-1);
    const float* xb = xyz + (size_t)b * NN * 3;
    const float* sb = sq + (size_t)b * NN;
    float qx = xb[n*3+0], qy = xb[n*3+1], qz = xb[n*3+2];
    float qs = sb[n];
    unsigned long long pk[32];
#pragma unroll
    for (int j = 0; j < 32; ++j) {
        int m = lane + 64*j;
        float mx = xb[m*3+0], my = xb[m*3+1], mz = xb[m*3+2];
        float dot = qx*mx + qy*my + qz*mz;
        float d = qs + sb[m] - 2.0f*dot;
        unsigned u = __float_as_uint(d);
        u ^= (u & 0x80000000u) ? 0xffffffffu : 0x80000000u;
        pk[j] = ((unsigned long long)u << 32) | (unsigned)m;
    }
    unsigned long long prev = 0;
    int* out = knn + (size_t)p * KK;
    for (int r = 0; r < KK; ++r) {
        unsigned long long best = ~0ull;
#pragma unroll
        for (int j = 0; j < 32; ++j) {
            unsigned long long c = (pk[j] > prev) ? pk[j] : ~0ull;
            best = (c < best) ? c : best;
        }
#pragma unroll
        for (int off = 32; off >= 1; off >>= 1) {
            unsigned long long o = __shfl_xor(best, off, 64);
            best = (o < best) ? o : best;
        }
        if (lane == 0) out[r] = (int)(best & 0xffffffffu);
        prev = best;
    }
}

// ---------------- kernel 3: x = features @ fc1_w + fc1_b ----------------
__global__ __launch_bounds__(256) void k_fc1(const float* __restrict__ feat,
                                             const float* __restrict__ w,
                                             const float* __restrict__ bias,
                                             float* __restrict__ x) {
    __shared__ float ft[DPTS*36];
    int tid = threadIdx.x;
    size_t row0 = (size_t)blockIdx.x * 32;
#pragma unroll
    for (int j = 0; j < 16; ++j) {
        int i = tid + 256*j;
        int r = i >> 7, k = i & 127;
        ft[k*36 + r] = feat[row0*DPTS + i];
    }
    __syncthreads();
    int rg = tid >> 6, cg = tid & 63;
    int r0 = rg*8, c0 = cg*4;
    float4 bv = *(const float4*)(bias + c0);
    float acc[8][4];
#pragma unroll
    for (int i = 0; i < 8; ++i) { acc[i][0]=bv.x; acc[i][1]=bv.y; acc[i][2]=bv.z; acc[i][3]=bv.w; }
#pragma unroll 4
    for (int k = 0; k < DPTS; ++k) {
        float4 a0 = *(const float4*)(ft + k*36 + r0);
        float4 a1 = *(const float4*)(ft + k*36 + r0 + 4);
        float4 wv = *(const float4*)(w + (size_t)k*DM + c0);
        float av[8] = {a0.x,a0.y,a0.z,a0.w,a1.x,a1.y,a1.z,a1.w};
#pragma unroll
        for (int i = 0; i < 8; ++i) {
            acc[i][0] += av[i]*wv.x; acc[i][1] += av[i]*wv.y;
            acc[i][2] += av[i]*wv.z; acc[i][3] += av[i]*wv.w;
        }
    }
#pragma unroll
    for (int i = 0; i < 8; ++i)
        *(float4*)(x + (row0 + r0 + i)*DM + c0) =
            make_float4(acc[i][0],acc[i][1],acc[i][2],acc[i][3]);
}

// ---------------- kernel 4: q/k/v = x @ {wq,wk,wv} ----------------
__global__ __launch_bounds__(256) void k_qkv(const float* __restrict__ x,
                                             const float* __restrict__ wq,
                                             const float* __restrict__ wk,
                                             const float* __restrict__ wv,
                                             float* __restrict__ q,
                                             float* __restrict__ kb,
                                             float* __restrict__ vb) {
    __shared__ float xt[DM*36];
    int tid = threadIdx.x;
    size_t row0 = (size_t)blockIdx.x * 32;
#pragma unroll
    for (int j = 0; j < 32; ++j) {
        int i = tid + 256*j;
        int r = i >> 8, k = i & 255;
        xt[k*36 + r] = x[row0*DM + i];
    }
    __syncthreads();
    int rg = tid >> 6, cg = tid & 63;
    int r0 = rg*8, c0 = cg*4;
    for (int m = 0; m < 3; ++m) {
        const float* w = (m==0) ? wq : ((m==1) ? wk : wv);
        float* o = (m==0) ? q : ((m==1) ? kb : vb);
        float acc[8][4];
#pragma unroll
        for (int i = 0; i < 8; ++i) { acc[i][0]=0.f; acc[i][1]=0.f; acc[i][2]=0.f; acc[i][3]=0.f; }
#pragma unroll 4
        for (int k = 0; k < DM; ++k) {
            float4 a0 = *(const float4*)(xt + k*36 + r0);
            float4 a1 = *(const float4*)(xt + k*36 + r0 + 4);
            float4 wv4 = *(const float4*)(w + (size_t)k*DM + c0);
            float av[8] = {a0.x,a0.y,a0.z,a0.w,a1.x,a1.y,a1.z,a1.w};
#pragma unroll
            for (int i = 0; i < 8; ++i) {
                acc[i][0] += av[i]*wv4.x; acc[i][1] += av[i]*wv4.y;
                acc[i][2] += av[i]*wv4.z; acc[i][3] += av[i]*wv4.w;
            }
        }
#pragma unroll
        for (int i = 0; i < 8; ++i)
            *(float4*)(o + (row0 + r0 + i)*DM + c0) =
                make_float4(acc[i][0],acc[i][1],acc[i][2],acc[i][3]);
    }
}

// ---------------- kernel 5: fused attn, MFMA phases C/E/F ----------------
// LDS map (33344 B -> 4 WG/CU):
//   [0,64)      kidx
//   [64,320)    rel [16][4]
//   [320,8512)  hidT: hidden^T bf16 [16][256] swz  -> reused as T bf16 [64][64] swz
//   [8512,25152) posf fp32 [16][260]              -> reused as L fp32 [64][65]
//   [25152,33344) Abuf bf16 [64][64] swz
// bf16 LDS tiles use byte ^= ((row&7)<<4) XOR swizzle (G4) for conflict-free
// b128 fragment reads. 4 barriers total; C->D, E->F are wave-local (no barrier).
__global__ __launch_bounds__(256, 4) void k_attn(
    const float* __restrict__ xyz, const float* __restrict__ qbuf,
    const float* __restrict__ kbuf, const float* __restrict__ vbuf,
    const int* __restrict__ knn,
    const float* __restrict__ dw1, const float* __restrict__ db1,
    const short8_t* __restrict__ dw2b, const float* __restrict__ db2,
    const short8_t* __restrict__ gw1b, const float* __restrict__ gb1,
    const short8_t* __restrict__ gw2b, const float* __restrict__ gb2,
    float* __restrict__ res, float* __restrict__ attn_out)
{
    __shared__ __align__(16) unsigned char smem[33344];
    int*   kidx = (int*)(smem + 0);
    float* relp = (float*)(smem + 64);
    unsigned char* hidT = smem + 320;
    float* posf = (float*)(smem + 8512);
    unsigned char* Abuf = smem + 25152;

    int tid = threadIdx.x;
    int l = tid & 63, w = tid >> 6;
    int p = blockIdx.x, b = p >> 11, n = p & (NN-1);
    size_t pb = (size_t)p;

    float qc = qbuf[pb*DM + tid];
    if (tid < KK) kidx[tid] = knn[pb*KK + tid];
    __syncthreads();
    if (tid < KK*3) {
        int k = tid/3, ax = tid%3;
        relp[k*4+ax] = xyz[((size_t)b*NN + n)*3 + ax]
                     - xyz[((size_t)b*NN + kidx[k])*3 + ax];
    }
    __syncthreads();

    // B: hidden = relu(rel@dw1+db1), thread owns column c=tid, 16 k values
    {
        float w0 = dw1[tid], w1 = dw1[DM+tid], w2 = dw1[2*DM+tid], bb = db1[tid];
#pragma unroll
        for (int k = 0; k < KK; ++k) {
            float t = fmaxf(relp[k*4]*w0 + relp[k*4+1]*w1 + relp[k*4+2]*w2 + bb, 0.f);
            *(unsigned short*)(hidT + k*512 + ((2*tid) ^ ((k&7)<<4))) = f2b(t);
        }
    }
    __syncthreads();

    // C: pos = hidden @ dw2 + db2 via MFMA. Wave w owns cols [w*64, w*64+64).
    {
        f32x4 acc[4];
#pragma unroll
        for (int ci = 0; ci < 4; ++ci) {
            float bias = db2[(w*4+ci)*16 + (l&15)];
            acc[ci] = (f32x4){bias, bias, bias, bias};
        }
#pragma unroll
        for (int kc = 0; kc < 8; ++kc) {
            int ar = l & 15;
            short8_t a = *(const short8_t*)(hidT + ar*512 +
                          ((kc*64 + (l>>4)*16) ^ ((ar&7)<<4)));
#pragma unroll
            for (int ci = 0; ci < 4; ++ci) {
                short8_t bf = dw2b[((size_t)(w*4+ci)*8 + kc)*64 + l];
                acc[ci] = __builtin_amdgcn_mfma_f32_16x16x32_bf16(a, bf, acc[ci], 0, 0, 0);
            }
        }
#pragma unroll
        for (int ci = 0; ci < 4; ++ci)
#pragma unroll
            for (int r = 0; r < 4; ++r)
                posf[((l>>4)*4 + r)*260 + (w*4+ci)*16 + (l&15)] = acc[ci][r];
    }
    // no barrier: D reads pos cols [w*64, w*64+64) written by this same wave

    // D: gather k/v rows; A = (q - k) + pos -> bf16 Abuf; vnr = v + pos (fp32)
    float vnr[KK];
    {
#pragma unroll
        for (int k = 0; k < KK; ++k) {
            size_t g = ((size_t)b*NN + kidx[k])*DM + tid;
            float kv = kbuf[g], vv = vbuf[g];
            float pv = posf[k*260 + tid];
            vnr[k] = vv + pv;
            int row = 4*k + w;
            *(unsigned short*)(Abuf + row*128 + ((2*l) ^ ((row&7)<<4))) =
                f2b((qc - kv) + pv);
        }
    }
    __syncthreads();

    // E: T = relu(A @ gw1 + gb1). Wave w owns rows [w*16, w*16+16). T -> hidT.
    {
        f32x4 acc[4];
#pragma unroll
        for (int ci = 0; ci < 4; ++ci) {
            float bias = gb1[ci*16 + (l&15)];
            acc[ci] = (f32x4){bias, bias, bias, bias};
        }
#pragma unroll
        for (int kc = 0; kc < 2; ++kc) {
            int row = w*16 + (l & 15);
            short8_t a = *(const short8_t*)(Abuf + row*128 +
                          ((kc*64 + (l>>4)*16) ^ ((row&7)<<4)));
#pragma unroll
            for (int ci = 0; ci < 4; ++ci) {
                short8_t bf = gw1b[(ci*2 + kc)*64 + l];
                acc[ci] = __builtin_amdgcn_mfma_f32_16x16x32_bf16(a, bf, acc[ci], 0, 0, 0);
            }
        }
#pragma unroll
        for (int ci = 0; ci < 4; ++ci)
#pragma unroll
            for (int r = 0; r < 4; ++r) {
                int row = w*16 + (l>>4)*4 + r, col = ci*16 + (l&15);
                *(unsigned short*)(hidT + row*128 + ((2*col) ^ ((row&7)<<4))) =
                    f2b(fmaxf(acc[ci][r], 0.f));
            }
    }
    // no barrier: F reads T rows [w*16, w*16+16) written by this same wave

    // F: L = T @ gw2 + gb2 -> fp32 [64][65] into posf region
    {
        f32x4 acc[4];
#pragma unroll
        for (int ci = 0; ci < 4; ++ci) {
            float bias = gb2[ci*16 + (l&15)];
            acc[ci] = (f32x4){bias, bias, bias, bias};
        }
#pragma unroll
        for (int kc = 0; kc < 2; ++kc) {
            int row = w*16 + (l & 15);
            short8_t a = *(const short8_t*)(hidT + row*128 +
                          ((kc*64 + (l>>4)*16) ^ ((row&7)<<4)));
#pragma unroll
            for (int ci = 0; ci < 4; ++ci) {
                short8_t bf = gw2b[(ci*2 + kc)*64 + l];
                acc[ci] = __builtin_amdgcn_mfma_f32_16x16x32_bf16(a, bf, acc[ci], 0, 0, 0);
            }
        }
#pragma unroll
        for (int ci = 0; ci < 4; ++ci)
#pragma unroll
            for (int r = 0; r < 4; ++r) {
                int row = w*16 + (l>>4)*4 + r, col = ci*16 + (l&15);
                posf[row*65 + col] = acc[ci][r];
            }
    }
    __syncthreads();

    // G: softmax over k per (head w, dim l); write attn_out (streaming)
    float attnv[KK];
    {
        float s[KK];
#pragma unroll
        for (int k = 0; k < KK; ++k) s[k] = posf[(4*k + w)*65 + l] * 0.125f;
        float mx = s[0];
#pragma unroll
        for (int k = 1; k < KK; ++k) mx = fmaxf(mx, s[k]);
        float sum = 0.f;
#pragma unroll
        for (int k = 0; k < KK; ++k) { s[k] = __expf(s[k]-mx); sum += s[k]; }
        float inv = 1.0f / sum;
        size_t base = (((size_t)(b*HH + w)*NN + n)*KK)*HD + l;
#pragma unroll
        for (int k = 0; k < KK; ++k) {
            attnv[k] = s[k]*inv;
            __builtin_nontemporal_store(attnv[k], attn_out + base + (size_t)k*HD);
        }
    }
    // H: res = sum_k attn * (v + pos)   (vnr already holds v+pos, fp32)
    {
        float r = 0.f;
#pragma unroll
        for (int k = 0; k < KK; ++k) r += attnv[k]*vnr[k];
        res[pb*DM + tid] = r;
    }
}

// ---------------- kernel 6: proj -> LN1 -> fc2 -> LN2 -> +features ----------------
__global__ __launch_bounds__(256) void k_final(
    const float* __restrict__ resbuf, const float* __restrict__ feat,
    const float* __restrict__ proj_w,
    const float* __restrict__ fc2_w, const float* __restrict__ fc2_b,
    const float* __restrict__ ln1g, const float* __restrict__ ln1b,
    const float* __restrict__ ln2g, const float* __restrict__ ln2b,
    float* __restrict__ out)
{
    __shared__ float rT[DM*17];
    __shared__ float y[16*260];
    __shared__ float z[16*132];
    __shared__ float stats[16][2];
    int tid = threadIdx.x;
    size_t row0 = (size_t)blockIdx.x * 16;

#pragma unroll
    for (int j = 0; j < 16; ++j)
        rT[tid*17 + j] = resbuf[(row0+j)*DM + tid];
    __syncthreads();

    int rg = tid >> 6, cg = tid & 63;
    int r0 = rg*4, c0 = cg*4;
    {
        float acc[4][4];
#pragma unroll
        for (int i=0;i<4;++i){acc[i][0]=0.f;acc[i][1]=0.f;acc[i][2]=0.f;acc[i][3]=0.f;}
#pragma unroll 4
        for (int h = 0; h < DM; ++h) {
            float avv[4];
#pragma unroll
            for (int i=0;i<4;++i) avv[i] = rT[h*17 + r0 + i];
            float4 wv = *(const float4*)(proj_w + (size_t)h*DM + c0);
#pragma unroll
            for (int i=0;i<4;++i){
                acc[i][0]+=avv[i]*wv.x; acc[i][1]+=avv[i]*wv.y;
                acc[i][2]+=avv[i]*wv.z; acc[i][3]+=avv[i]*wv.w;
            }
        }
#pragma unroll
        for (int i=0;i<4;++i)
            *(float4*)(y + (r0+i)*260 + c0) =
                make_float4(acc[i][0],acc[i][1],acc[i][2],acc[i][3]);
    }
    __syncthreads();

    {
        int ww = tid >> 6, lane = tid & 63;
#pragma unroll
        for (int i = 0; i < 4; ++i) {
            int r = ww*4 + i;
            float4 v = *(const float4*)(y + r*260 + lane*4);
            float sm = v.x+v.y+v.z+v.w;
#pragma unroll
            for (int off = 32; off >= 1; off >>= 1) sm += __shfl_xor(sm, off, 64);
            float mean = sm * (1.0f/256.0f);
            float dx = v.x-mean, dy = v.y-mean, dz = v.z-mean, dw = v.w-mean;
            float vs = dx*dx+dy*dy+dz*dz+dw*dw;
#pragma unroll
            for (int off = 32; off >= 1; off >>= 1) vs += __shfl_xor(vs, off, 64);
            float var = vs * (1.0f/256.0f);
            if (lane == 0) { stats[r][0] = mean; stats[r][1] = 1.0f/sqrtf(var + 1e-5f); }
        }
    }
    __syncthreads();
    {
        float g = ln1g[tid], bb = ln1b[tid];
#pragma unroll
        for (int j = 0; j < 16; ++j) {
            float m = stats[j][0], rs = stats[j][1];
            y[j*260 + tid] = (y[j*260 + tid] - m)*rs*g + bb;
        }
    }
    __syncthreads();

    {
        int rg2 = tid >> 5, cg2 = tid & 31;
        int rr0 = rg2*2, cc0 = cg2*4;
        float4 bv = *(const float4*)(fc2_b + cc0);
        float acc[2][4];
#pragma unroll
        for (int i=0;i<2;++i){acc[i][0]=bv.x;acc[i][1]=bv.y;acc[i][2]=bv.z;acc[i][3]=bv.w;}
#pragma unroll 4
        for (int h = 0; h < DM; ++h) {
            float a0 = y[(rr0+0)*260 + h];
            float a1 = y[(rr0+1)*260 + h];
            float4 wv = *(const float4*)(fc2_w + (size_t)h*DPTS + cc0);
            acc[0][0]+=a0*wv.x; acc[0][1]+=a0*wv.y; acc[0][2]+=a0*wv.z; acc[0][3]+=a0*wv.w;
            acc[1][0]+=a1*wv.x; acc[1][1]+=a1*wv.y; acc[1][2]+=a1*wv.z; acc[1][3]+=a1*wv.w;
        }
#pragma unroll
        for (int i=0;i<2;++i)
            *(float4*)(z + (rr0+i)*132 + cc0) =
                make_float4(acc[i][0],acc[i][1],acc[i][2],acc[i][3]);
    }
    __syncthreads();

    {
        int ww = tid >> 6, lane = tid & 63;
#pragma unroll
        for (int i = 0; i < 4; ++i) {
            int r = ww*4 + i;
            float2 v = *(const float2*)(z + r*132 + lane*2);
            float sm = v.x + v.y;
#pragma unroll
            for (int off = 32; off >= 1; off >>= 1) sm += __shfl_xor(sm, off, 64);
            float mean = sm * (1.0f/128.0f);
            float dx = v.x-mean, dy = v.y-mean;
            float vs = dx*dx + dy*dy;
#pragma unroll
            for (int off = 32; off >= 1; off >>= 1) vs += __shfl_xor(vs, off, 64);
            float var = vs * (1.0f/128.0f);
            if (lane == 0) { stats[r][0] = mean; stats[r][1] = 1.0f/sqrtf(var + 1e-5f); }
        }
    }
    __syncthreads();
    {
        int hh = tid & 127;
        float g = ln2g[hh], bb = ln2b[hh];
#pragma unroll
        for (int j = 0; j < 8; ++j) {
            int r = (tid >> 7) + 2*j;
            float m = stats[r][0], rs = stats[r][1];
            float val = (z[r*132 + hh] - m)*rs*g + bb + feat[(row0+r)*DPTS + hh];
            out[(row0+r)*DPTS + hh] = val;
        }
    }
}

// ---------------- launcher ----------------
extern "C" void kernel_launch(void* const* d_in, const int* in_sizes, int n_in,
                              void* d_out, int out_size, void* d_ws, size_t ws_size,
                              hipStream_t stream)
{
    (void)in_sizes; (void)n_in; (void)out_size; (void)ws_size;
    const float* xyz      = (const float*)d_in[0];
    const float* features = (const float*)d_in[1];
    const float* fc1_w    = (const float*)d_in[2];
    const float* fc1_b    = (const float*)d_in[3];
    const float* fc2_w    = (const float*)d_in[4];
    const float* fc2_b    = (const float*)d_in[5];
    const float* dw1      = (const float*)d_in[6];
    const float* db1      = (const float*)d_in[7];
    const float* dw2      = (const float*)d_in[8];
    const float* db2      = (const float*)d_in[9];
    const float* gw1      = (const float*)d_in[10];
    const float* gb1      = (const float*)d_in[11];
    const float* gw2      = (const float*)d_in[12];
    const float* gb2      = (const float*)d_in[13];
    const float* wq       = (const float*)d_in[14];
    const float* wk       = (const float*)d_in[15];
    const float* wv       = (const float*)d_in[16];
    const float* proj_w   = (const float*)d_in[17];
    const float* ln1g     = (const float*)d_in[18];
    const float* ln1b     = (const float*)d_in[19];
    const float* ln2g     = (const float*)d_in[20];
    const float* ln2b     = (const float*)d_in[21];
    float* out = (float*)d_out;

    char* ws = (char*)d_ws;
    float* sq   = (float*)(ws + 0);          //  64 KB
    int*   knn  = (int*)  (ws + 65536);      //   1 MB
    float* xbuf = (float*)(ws + 1114112);    //  16 MB (aliased as res later)
    float* qb   = (float*)(ws + 17891328);   //  16 MB
    float* kb   = (float*)(ws + 34668544);   //  16 MB
    float* vb   = (float*)(ws + 51445760);   //  16 MB
    short8_t* dw2b = (short8_t*)(ws + 68222976);   // 128 KB
    short8_t* gw1b = (short8_t*)(ws + 68354048);   //   8 KB
    short8_t* gw2b = (short8_t*)(ws + 68362240);   //   8 KB
    float* resb = xbuf;

    k_prep<<<36,     256, 0, stream>>>(dw2, gw1, gw2, dw2b, gw1b, gw2b);
    k_sq  <<<BN/256, 256, 0, stream>>>(xyz, sq);
    k_knn <<<BN/4,   256, 0, stream>>>(xyz, sq, knn);
    k_fc1 <<<BN/32,  256, 0, stream>>>(features, fc1_w, fc1_b, xbuf);
    k_qkv <<<BN/32,  256, 0, stream>>>(xbuf, wq, wk, wv, qb, kb, vb);
    k_attn<<<BN,     256, 0, stream>>>(xyz, qb, kb, vb, knn,
                                       dw1, db1, dw2b, db2,
                                       gw1b, gb1, gw2b, gb2,
                                       resb, out + (size_t)BN*DPTS);
    k_final<<<BN/16, 256, 0, stream>>>(resb, features, proj_w, fc2_w, fc2_b,
                                       ln1g, ln1b, ln2g, ln2b, out);
}